// Round 10
// baseline (185.082 us; speedup 1.0000x reference)
//
#include <hip/hip_runtime.h>
#include <cstdint>
#include <cmath>

// Problem constants
#define NB 2
#define NC 256
#define HW 2304          // 48*48
#define HID 64
#define OH 96
#define OW 96
#define N1 9216          // 96*96
#define SCALE_ATTN 0.17677669529663689f   // 32^-0.5
#define RESZ ((float)(47.0/95.0))

// oc-group split for k34 phase B: waves {0,1} take 5 ocs, {2,3} take 4
__device__ __host__ inline int ocb_of(int w) { return w < 2 ? w * 5 : 10 + (w - 2) * 4; }
__device__ __host__ inline int cnt_of(int w) { return w < 2 ? 5 : 4; }

// ---------------- KA: fused prep.
// blk<1152: x NCHW -> v_nhwc [4][2304][128] (LDS-tiled transpose).
// else: WT4[c4][128][4]; dwT[tap][32]; wg[4][288][5] (zero-padded); bsg[20]
__global__ void kA_prep(const float* __restrict__ x, const float* __restrict__ Wq,
                        const float* __restrict__ Wk, const float* __restrict__ off_w,
                        const float* __restrict__ dw_w, const float* __restrict__ off_b,
                        float* __restrict__ v_nhwc, float* __restrict__ WT4,
                        float* __restrict__ dwT, float* __restrict__ wg,
                        float* __restrict__ bsg) {
    int blk = blockIdx.x;
    if (blk < 1152) {
        int pt = blk % 72;
        int t2 = blk / 72;
        int ct = t2 & 3;
        int bg = t2 >> 2;
        int b = bg >> 1, g = bg & 1;
        __shared__ float tile[32][33];
        int tx = threadIdx.x & 31, row = threadIdx.x >> 5;   // row 0..7
#pragma unroll
        for (int r = 0; r < 4; r++) {
            int c = ct * 32 + row + r * 8;
            tile[row + r * 8][tx] = x[((size_t)(b * 256 + g * 128 + c)) * HW + pt * 32 + tx];
        }
        __syncthreads();
#pragma unroll
        for (int r = 0; r < 4; r++) {
            int p = pt * 32 + row + r * 8;
            v_nhwc[((size_t)bg * HW + p) * 128 + ct * 32 + tx] = tile[tx][row + r * 8];
        }
    } else {
        int idx = (blk - 1152) * 256 + threadIdx.x;
        if (idx < 256 * 128) {
            int c = idx >> 7, t = idx & 127;
            float v = (t < 64) ? Wq[t * 256 + c] : Wk[(t - 64) * 256 + c];
            WT4[(((size_t)(c >> 2) * 128) + t) * 4 + (c & 3)] = v;
        } else if (idx < 256 * 128 + 288) {
            int i = idx - 256 * 128;
            int wi = i >> 5, c = i & 31;
            dwT[i] = dw_w[c * 9 + wi];
        } else if (idx < 256 * 128 + 288 + 4 * 288 * 5) {
            int i = idx - (256 * 128 + 288);
            int w = i / 1440, r = i - w * 1440;
            int kk = r / 5, j = r - kk * 5;
            wg[i] = (j < cnt_of(w)) ? off_w[(ocb_of(w) + j) * 288 + kk] : 0.f;
        } else if (idx < 256 * 128 + 288 + 4 * 288 * 5 + 20) {
            int i = idx - (256 * 128 + 288 + 4 * 288 * 5);
            int w = i / 5, j = i - w * 5;
            bsg[i] = (j < cnt_of(w)) ? off_b[ocb_of(w) + j] : 0.f;
        }
    }
}

// ---------------- K1: channel LN over 256 + Q/K projection, reading coalesced v_nhwc.
// Block = 256 thr = 4 pixels. LN: one wave per pixel, shfl butterfly only.
__global__ __launch_bounds__(256) void k1_ln_qk(const float* __restrict__ v_nhwc,
                         const float* __restrict__ ln_g, const float* __restrict__ ln_b,
                         const float* __restrict__ WT4,
                         float* __restrict__ q_pix, float* __restrict__ k_nhwc) {
    int blk = blockIdx.x;            // 0..1151
    int tid = threadIdx.x;
    int wv = tid >> 6, lane = tid & 63;
    __shared__ float xs[4][256];
    {
        int pix = blk * 4 + wv;
        int b = pix / HW, p = pix - b * HW;
        int c0 = lane * 2;
        float2 u0 = *(const float2*)(v_nhwc + (((size_t)(b * 2 + 0) * HW) + p) * 128 + c0);
        float2 u1 = *(const float2*)(v_nhwc + (((size_t)(b * 2 + 1) * HW) + p) * 128 + c0);
        float s = u0.x + u0.y + u1.x + u1.y;
#pragma unroll
        for (int off = 1; off < 64; off <<= 1) s += __shfl_xor(s, off);
        float mu = s * (1.f / 256.f);
        float d0 = u0.x - mu, d1 = u0.y - mu, d2 = u1.x - mu, d3 = u1.y - mu;
        float q = d0 * d0 + d1 * d1 + d2 * d2 + d3 * d3;
#pragma unroll
        for (int off = 1; off < 64; off <<= 1) q += __shfl_xor(q, off);
        float rs = rsqrtf(q * (1.f / 256.f) + 1e-5f);
        float2 w0, w1;
        w0.x = d0 * rs * ln_g[c0] + ln_b[c0];
        w0.y = d1 * rs * ln_g[c0 + 1] + ln_b[c0 + 1];
        w1.x = d2 * rs * ln_g[128 + c0] + ln_b[128 + c0];
        w1.y = d3 * rs * ln_g[129 + c0] + ln_b[129 + c0];
        *(float2*)&xs[wv][c0] = w0;
        *(float2*)&xs[wv][128 + c0] = w1;
    }
    __syncthreads();
    int o = tid & 127, ph = tid >> 7;
    float a0 = 0.f, a1 = 0.f;
    const float4* wp = (const float4*)WT4 + o;         // stride 128 float4s per c4
    const float4* xa = (const float4*)xs[ph * 2];
    const float4* xb4 = (const float4*)xs[ph * 2 + 1];
#pragma unroll 8
    for (int c4 = 0; c4 < 64; c4++) {
        float4 w = wp[(size_t)c4 * 128];
        float4 p0 = xa[c4], p1 = xb4[c4];
        a0 += w.x * p0.x + w.y * p0.y + w.z * p0.z + w.w * p0.w;
        a1 += w.x * p1.x + w.y * p1.y + w.z * p1.z + w.w * p1.w;
    }
#pragma unroll
    for (int k = 0; k < 2; k++) {
        int pix = blk * 4 + ph * 2 + k;
        int b = pix / HW, p = pix - b * HW;
        float a = k ? a1 : a0;
        if (o < 64) {
            q_pix[(((size_t)b * HW) + p) * 64 + o] = a;
        } else {
            int t = o - 64, g = t >> 5, c32 = t & 31;
            k_nhwc[(((size_t)(b * 2 + g) * HW) + p) * 32 + c32] = a;
        }
    }
}

// ---------------- K34: fused offset branch.
// Grid: 4 bg x 144 tiles (8x8 px) = 576 blocks.
// Phase A: thread-per-(halo point, channel): dw3x3(resize(q)) + LN(32, shfl) + GELU
//          -> LDS ts[100][33] (10x10 halo, pitch 33).
// Phase B: wave w owns oc-group (5/5/4/4); lane = pixel; wave-uniform weights from wg.
__global__ __launch_bounds__(256) void k34_off(const float* __restrict__ q_pix,
                                               const float* __restrict__ dwT,
                                               const float* __restrict__ og,
                                               const float* __restrict__ ob,
                                               const float* __restrict__ wg,
                                               const float* __restrict__ bsg,
                                               float* __restrict__ pred) {
    int blk = blockIdx.x;
    int bg = blk / 144, tile = blk - bg * 144;
    int ty0 = (tile / 12) * 8, tx0 = (tile % 12) * 8;
    int b = bg >> 1, g = bg & 1;
    int tid = threadIdx.x;
    __shared__ float ts[100 * 33];

    const float* qb = q_pix + ((size_t)b * HW) * 64 + g * 32;
    for (int item = tid; item < 3200; item += 256) {
        int pt = item >> 5, c = item & 31;     // pt uniform per 32-lane half
        int pyh = pt / 10, pxh = pt - pyh * 10;
        int hy = ty0 + pyh - 1, hx = tx0 + pxh - 1;
        bool inb = ((unsigned)hy < (unsigned)OH) && ((unsigned)hx < (unsigned)OW);
        float acc = 0.f;
        if (inb) {
#pragma unroll
            for (int dy = -1; dy <= 1; dy++) {
                int yy = hy + dy;
                if ((unsigned)yy >= (unsigned)OH) continue;
                float ysf = yy * RESZ;
                int y0 = min((int)ysf, 46);
                float wy = ysf - (float)y0;
#pragma unroll
                for (int dx = -1; dx <= 1; dx++) {
                    int xx = hx + dx;
                    if ((unsigned)xx >= (unsigned)OW) continue;
                    float xsf = xx * RESZ;
                    int x0 = min((int)xsf, 46);
                    float wx = xsf - (float)x0;
                    int i00 = (y0 * 48 + x0) * 64;
                    float q00 = qb[i00 + c], q01 = qb[i00 + 64 + c];
                    float q10 = qb[i00 + 48 * 64 + c], q11 = qb[i00 + 49 * 64 + c];
                    float qv = (q00 * (1.f - wy) + q10 * wy) * (1.f - wx)
                             + (q01 * (1.f - wy) + q11 * wy) * wx;
                    acc += qv * dwT[((dy + 1) * 3 + dx + 1) * 32 + c];
                }
            }
        }
        // LN over 32 channels — executed by ALL lanes (acc=0 when OOB; result masked)
        float s = acc;
#pragma unroll
        for (int off = 1; off < 32; off <<= 1) s += __shfl_xor(s, off);
        float mu = s * (1.f / 32.f);
        float d = acc - mu;
        float v = d * d;
#pragma unroll
        for (int off = 1; off < 32; off <<= 1) v += __shfl_xor(v, off);
        float rsv = rsqrtf(v * (1.f / 32.f) + 1e-5f);
        float t = d * rsv * og[c] + ob[c];
        float ge = 0.5f * t * (1.f + erff(t * 0.70710678118654752f));
        ts[pt * 33 + c] = inb ? ge : 0.f;
    }
    __syncthreads();

    int w = __builtin_amdgcn_readfirstlane(tid >> 6);
    int lane = tid & 63;
    int y = lane >> 3, x = lane & 7;
    int ocb = ocb_of(w), cnt = cnt_of(w);
    float acc[5];
#pragma unroll
    for (int j = 0; j < 5; j++) acc[j] = bsg[w * 5 + j];
    const float* tsb = &ts[(y * 10 + x) * 33];
    const float* wgp = wg + (size_t)w * 1440;
    const int kof[9] = {0, 33, 66, 330, 363, 396, 660, 693, 726};
    for (int ic = 0; ic < 32; ic++) {
#pragma unroll
        for (int k = 0; k < 9; k++) {
            float tv = tsb[kof[k] + ic];
            const float* wr = wgp + (ic * 9 + k) * 5;
#pragma unroll
            for (int j = 0; j < 5; j++) acc[j] += tv * wr[j];
        }
    }
    int p = (ty0 + y) * OW + tx0 + x;
    float* pp = pred + ((size_t)bg * N1 + p) * 18 + ocb;
#pragma unroll
    for (int j = 0; j < 5; j++)
        if (j < cnt) pp[j] = acc[j];
}

// ---------------- K5: deformable attention. 1 wave = 4 consecutive pixels (same row);
// block = 16 pixels. q resized on the fly; softmax in-register; per-lane float4 v-loads.
__global__ __launch_bounds__(256) void k5_attn(const float* __restrict__ pred,
                                               const float* __restrict__ q_pix,
                                               const float* __restrict__ k_nhwc,
                                               const float* __restrict__ v_nhwc,
                                               const float* __restrict__ rpb,
                                               float* __restrict__ out) {
    int tid = threadIdx.x;
    int wv = __builtin_amdgcn_readfirstlane(tid >> 6);
    int lane = tid & 63;
    int gp = blockIdx.x * 16;              // block-base pixel (same bg, same row)
    int bg = gp / N1, p0 = gp % N1;
    int b = bg >> 1, g = bg & 1;
    int pw = p0 + wv * 4;                  // wave-base pixel
    int oy = pw / OW, ox0 = pw % OW;

    __shared__ float4 wts[4][4][9];        // [wave][px][tap] corner weights
    __shared__ int4   cof[4][4][9];        // [wave][px][tap] corner pixel offsets
    __shared__ float  outb[4][4][128];     // [wave][px][ch]

    // --- tap setup: lanes 0..35 -> (px, j)
    if (lane < 36) {
        int px = lane / 9, j = lane % 9;
        int p = pw + px;
        int ky = j / 3, kx = j % 3;
        const float* pp = pred + ((size_t)bg * N1 + p) * 18;
        float pr0 = pp[j * 2];
        float pr1 = pp[j * 2 + 1];
        float th0 = 1.f - 2.f * __builtin_amdgcn_rcpf(__expf(2.f * pr0) + 1.f);
        float th1 = 1.f - 2.f * __builtin_amdgcn_rcpf(__expf(2.f * pr1) + 1.f);
        float py  = th0 * 11.0f + (float)(ky - 1) + (float)oy;
        float pxc = th1 * 11.0f + (float)(kx - 1) + (float)(ox0 + px);
        float iy = py * RESZ, ix = pxc * RESZ;
        float y0f = floorf(iy), x0f = floorf(ix);
        float wy = iy - y0f, wx = ix - x0f;
        int y0 = (int)y0f, x0 = (int)x0f;
        bool vy0 = (unsigned)y0 < 48u, vy1 = (unsigned)(y0 + 1) < 48u;
        bool vx0 = (unsigned)x0 < 48u, vx1 = (unsigned)(x0 + 1) < 48u;
        int y0c = min(max(y0, 0), 47), y1c = min(max(y0 + 1, 0), 47);
        int x0c = min(max(x0, 0), 47), x1c = min(max(x0 + 1, 0), 47);
        float4 w;
        w.x = (vy0 && vx0) ? (1.f - wy) * (1.f - wx) : 0.f;
        w.y = (vy0 && vx1) ? (1.f - wy) * wx : 0.f;
        w.z = (vy1 && vx0) ? wy * (1.f - wx) : 0.f;
        w.w = (vy1 && vx1) ? wy * wx : 0.f;
        wts[wv][px][j] = w;
        cof[wv][px][j] = make_int4(y0c * 48 + x0c, y0c * 48 + x1c,
                                   y1c * 48 + x0c, y1c * 48 + x1c);
    }
    __syncthreads();

    int c = lane & 31, h = lane >> 5;
    int c4 = (lane & 31) * 4;
    const float* kb = k_nhwc + (size_t)bg * HW * 32;
    const float* rb = rpb + (size_t)g * 288;
    const float* qb = q_pix + (size_t)b * HW * 64 + g * 32 + c;
    const float* vbase = v_nhwc + (size_t)bg * HW * 128;

    float ysf = oy * RESZ;
    int qy0 = min((int)ysf, 46);
    float qwy = ysf - (float)qy0;

    for (int px = 0; px < 4; px++) {
        // on-the-fly resized q (lane c channel)
        float xsf = (ox0 + px) * RESZ;
        int qx0 = min((int)xsf, 46);
        float qwx = xsf - (float)qx0;
        int qi = (qy0 * 48 + qx0) * 64;
        float q00 = qb[qi], q01 = qb[qi + 64];
        float q10 = qb[qi + 48 * 64], q11 = qb[qi + 49 * 64];
        float qv = ((q00 * (1.f - qwy) + q10 * qwy) * (1.f - qwx)
                  + (q01 * (1.f - qwy) + q11 * qwy) * qwx) * SCALE_ATTN;

        // scores: h-split taps; after xor-reduce all 32 lanes of a half hold the sum
        float s[5], e[5];
#pragma unroll
        for (int jj = 0; jj < 5; jj++) {
            int j = jj * 2 + h;
            float partial = 0.f;
            if (j < 9) {
                float4 w = wts[wv][px][j];
                int4 co = cof[wv][px][j];
                float kv = w.x * kb[co.x * 32 + c] + w.y * kb[co.y * 32 + c]
                         + w.z * kb[co.z * 32 + c] + w.w * kb[co.w * 32 + c];
                partial = qv * (kv + rb[j * 32 + c]);
            }
#pragma unroll
            for (int off = 1; off < 32; off <<= 1) partial += __shfl_xor(partial, off);
            s[jj] = (j < 9) ? partial : -1e30f;
        }
        // in-register softmax across both halves
        float m = s[0];
#pragma unroll
        for (int jj = 1; jj < 5; jj++) m = fmaxf(m, s[jj]);
        m = fmaxf(m, __shfl_xor(m, 32));
        float sum = 0.f;
#pragma unroll
        for (int jj = 0; jj < 5; jj++) { e[jj] = __expf(s[jj] - m); sum += e[jj]; }
        sum += __shfl_xor(sum, 32);
        float inv = __builtin_amdgcn_rcpf(sum);

        // value phase: float4 per lane over 128 ch, h-split taps
        float4 acc = make_float4(0.f, 0.f, 0.f, 0.f);
#pragma unroll
        for (int jj = 0; jj < 5; jj++) {
            int j = jj * 2 + h;
            if (j < 9) {
                float pj = e[jj] * inv;
                float4 w = wts[wv][px][j];
                int4 co = cof[wv][px][j];
                float4 a0 = *(const float4*)(vbase + (size_t)co.x * 128 + c4);
                float4 a1 = *(const float4*)(vbase + (size_t)co.y * 128 + c4);
                float4 a2 = *(const float4*)(vbase + (size_t)co.z * 128 + c4);
                float4 a3 = *(const float4*)(vbase + (size_t)co.w * 128 + c4);
                float f0 = w.x * pj, f1 = w.y * pj, f2 = w.z * pj, f3 = w.w * pj;
                acc.x += f0 * a0.x + f1 * a1.x + f2 * a2.x + f3 * a3.x;
                acc.y += f0 * a0.y + f1 * a1.y + f2 * a2.y + f3 * a3.y;
                acc.z += f0 * a0.z + f1 * a1.z + f2 * a2.z + f3 * a3.z;
                acc.w += f0 * a0.w + f1 * a1.w + f2 * a2.w + f3 * a3.w;
            }
        }
        acc.x += __shfl_xor(acc.x, 32);
        acc.y += __shfl_xor(acc.y, 32);
        acc.z += __shfl_xor(acc.z, 32);
        acc.w += __shfl_xor(acc.w, 32);
        if (lane < 32) *(float4*)&outb[wv][px][c4] = acc;
    }
    __syncthreads();

    // final write: thread ch<128 writes 4x float4 = 64B contiguous per channel
    if (tid < 128) {
        int ch = tid;
        float* op = out + ((size_t)b * NC + g * 128 + ch) * N1 + p0;
#pragma unroll
        for (int w2 = 0; w2 < 4; w2++) {
            float4 v4 = make_float4(outb[w2][0][ch], outb[w2][1][ch],
                                    outb[w2][2][ch], outb[w2][3][ch]);
            *(float4*)(op + w2 * 4) = v4;
        }
    }
}

extern "C" void kernel_launch(void* const* d_in, const int* in_sizes, int n_in,
                              void* d_out, int out_size, void* d_ws, size_t ws_size,
                              hipStream_t stream) {
    const float* x      = (const float*)d_in[0];
    const float* ln_g   = (const float*)d_in[1];
    const float* ln_b   = (const float*)d_in[2];
    const float* Wq     = (const float*)d_in[3];
    const float* Wk     = (const float*)d_in[4];
    const float* dw_w   = (const float*)d_in[5];
    const float* off_g  = (const float*)d_in[6];
    const float* off_bt = (const float*)d_in[7];
    const float* off_w  = (const float*)d_in[8];
    const float* off_b  = (const float*)d_in[9];
    const float* rpb    = (const float*)d_in[10];
    float* out = (float*)d_out;

    // Workspace layout (floats). Total = 2,471,860 floats = 9.43 MB. NO aliasing.
    float* ws = (float*)d_ws;
    float* v_nhwc = ws;                       // 1179648 [4][2304][128]
    float* WT4    = v_nhwc + 1179648;         // 32768   [64][128][4]
    float* k_nhwc = WT4 + 32768;              // 294912  [4][2304][32]
    float* q_pix  = k_nhwc + 294912;          // 294912  [2][2304][64]
    float* pred   = q_pix + 294912;           // 663552  [4][9216][18]
    float* dwT    = pred + 663552;            // 288     [9][32]
    float* wg     = dwT + 288;                // 5760    [4][288][5]
    float* bsg    = wg + 5760;                // 20      [4][5]

    kA_prep<<<1304, 256, 0, stream>>>(x, Wq, Wk, off_w, dw_w, off_b,
                                      v_nhwc, WT4, dwT, wg, bsg);
    k1_ln_qk<<<1152, 256, 0, stream>>>(v_nhwc, ln_g, ln_b, WT4, q_pix, k_nhwc);
    k34_off<<<576, 256, 0, stream>>>(q_pix, dwT, off_g, off_bt, wg, bsg, pred);
    k5_attn<<<2304, 256, 0, stream>>>(pred, q_pix, k_nhwc, v_nhwc, rpb, out);
}

// Round 11
// 166.732 us; speedup vs baseline: 1.1101x; 1.1101x over previous
//
#include <hip/hip_runtime.h>
#include <hip/hip_fp16.h>
#include <cstdint>
#include <cmath>

// Problem constants
#define NB 2
#define NC 256
#define HW 2304          // 48*48
#define HID 64
#define OH 96
#define OW 96
#define N1 9216          // 96*96
#define SCALE_ATTN 0.17677669529663689f   // 32^-0.5
#define RESZ ((float)(47.0/95.0))

// oc-group split for k4: 8 waves, counts {3,3,2,2,2,2,2,2}
__device__ __host__ inline int ocb8(int w) { return w < 2 ? 3 * w : 6 + 2 * (w - 2); }
__device__ __host__ inline int cnt8(int w) { return w < 2 ? 3 : 2; }

// ---------------- KA: fused prep.
// blk<1152: x NCHW -> v_nhwc [4][2304][128] (LDS-tiled transpose).
// else: WT4[c4][128][4]; dwT[tap][32]; wg2[8][288][3] (zero-padded); bsg2[24]
__global__ void kA_prep(const float* __restrict__ x, const float* __restrict__ Wq,
                        const float* __restrict__ Wk, const float* __restrict__ off_w,
                        const float* __restrict__ dw_w, const float* __restrict__ off_b,
                        float* __restrict__ v_nhwc, float* __restrict__ WT4,
                        float* __restrict__ dwT, float* __restrict__ wg2,
                        float* __restrict__ bsg2) {
    int blk = blockIdx.x;
    if (blk < 1152) {
        int pt = blk % 72;
        int t2 = blk / 72;
        int ct = t2 & 3;
        int bg = t2 >> 2;
        int b = bg >> 1, g = bg & 1;
        __shared__ float tile[32][33];
        int tx = threadIdx.x & 31, row = threadIdx.x >> 5;   // row 0..7
#pragma unroll
        for (int r = 0; r < 4; r++) {
            int c = ct * 32 + row + r * 8;
            tile[row + r * 8][tx] = x[((size_t)(b * 256 + g * 128 + c)) * HW + pt * 32 + tx];
        }
        __syncthreads();
#pragma unroll
        for (int r = 0; r < 4; r++) {
            int p = pt * 32 + row + r * 8;
            v_nhwc[((size_t)bg * HW + p) * 128 + ct * 32 + tx] = tile[tx][row + r * 8];
        }
    } else {
        int idx = (blk - 1152) * 256 + threadIdx.x;
        if (idx < 32768) {
            int c = idx >> 7, t = idx & 127;
            float v = (t < 64) ? Wq[t * 256 + c] : Wk[(t - 64) * 256 + c];
            WT4[(((size_t)(c >> 2) * 128) + t) * 4 + (c & 3)] = v;
        } else if (idx < 32768 + 288) {
            int i = idx - 32768;
            int wi = i >> 5, c = i & 31;
            dwT[i] = dw_w[c * 9 + wi];
        } else if (idx < 32768 + 288 + 8 * 288 * 3) {
            int i = idx - (32768 + 288);
            int w = i / 864, r = i - w * 864;
            int kk = r / 3, j = r - kk * 3;
            wg2[i] = (j < cnt8(w)) ? off_w[(ocb8(w) + j) * 288 + kk] : 0.f;
        } else if (idx < 32768 + 288 + 8 * 288 * 3 + 24) {
            int i = idx - (32768 + 288 + 8 * 288 * 3);
            int w = i / 3, j = i - w * 3;
            bsg2[i] = (j < cnt8(w)) ? off_b[ocb8(w) + j] : 0.f;
        }
    }
}

// ---------------- K1: channel LN over 256 + Q/K projection, reading coalesced v_nhwc.
__global__ __launch_bounds__(256) void k1_ln_qk(const float* __restrict__ v_nhwc,
                         const float* __restrict__ ln_g, const float* __restrict__ ln_b,
                         const float* __restrict__ WT4,
                         float* __restrict__ q_pix, float* __restrict__ k_nhwc) {
    int blk = blockIdx.x;            // 0..1151
    int tid = threadIdx.x;
    int wv = tid >> 6, lane = tid & 63;
    __shared__ float xs[4][256];
    {
        int pix = blk * 4 + wv;
        int b = pix / HW, p = pix - b * HW;
        int c0 = lane * 2;
        float2 u0 = *(const float2*)(v_nhwc + (((size_t)(b * 2 + 0) * HW) + p) * 128 + c0);
        float2 u1 = *(const float2*)(v_nhwc + (((size_t)(b * 2 + 1) * HW) + p) * 128 + c0);
        float s = u0.x + u0.y + u1.x + u1.y;
#pragma unroll
        for (int off = 1; off < 64; off <<= 1) s += __shfl_xor(s, off);
        float mu = s * (1.f / 256.f);
        float d0 = u0.x - mu, d1 = u0.y - mu, d2 = u1.x - mu, d3 = u1.y - mu;
        float q = d0 * d0 + d1 * d1 + d2 * d2 + d3 * d3;
#pragma unroll
        for (int off = 1; off < 64; off <<= 1) q += __shfl_xor(q, off);
        float rs = rsqrtf(q * (1.f / 256.f) + 1e-5f);
        float2 w0, w1;
        w0.x = d0 * rs * ln_g[c0] + ln_b[c0];
        w0.y = d1 * rs * ln_g[c0 + 1] + ln_b[c0 + 1];
        w1.x = d2 * rs * ln_g[128 + c0] + ln_b[128 + c0];
        w1.y = d3 * rs * ln_g[129 + c0] + ln_b[129 + c0];
        *(float2*)&xs[wv][c0] = w0;
        *(float2*)&xs[wv][128 + c0] = w1;
    }
    __syncthreads();
    int o = tid & 127, ph = tid >> 7;
    float a0 = 0.f, a1 = 0.f;
    const float4* wp = (const float4*)WT4 + o;         // stride 128 float4s per c4
    const float4* xa = (const float4*)xs[ph * 2];
    const float4* xb4 = (const float4*)xs[ph * 2 + 1];
#pragma unroll 8
    for (int c4 = 0; c4 < 64; c4++) {
        float4 w = wp[(size_t)c4 * 128];
        float4 p0 = xa[c4], p1 = xb4[c4];
        a0 += w.x * p0.x + w.y * p0.y + w.z * p0.z + w.w * p0.w;
        a1 += w.x * p1.x + w.y * p1.y + w.z * p1.z + w.w * p1.w;
    }
#pragma unroll
    for (int k = 0; k < 2; k++) {
        int pix = blk * 4 + ph * 2 + k;
        int b = pix / HW, p = pix - b * HW;
        float a = k ? a1 : a0;
        if (o < 64) {
            q_pix[(((size_t)b * HW) + p) * 64 + o] = a;
        } else {
            int t = o - 64, g = t >> 5, c32 = t & 31;
            k_nhwc[(((size_t)(b * 2 + g) * HW) + p) * 32 + c32] = a;
        }
    }
}

// ---------------- K3: t = GELU(LN(dw3x3(resize(q)))). Thread per (bg, pixel, ch).
// Wave = 2 pixels x 32 ch; LN via 32-lane-half shfl. Output fp16.
__global__ __launch_bounds__(256) void k3_t(const float* __restrict__ q_pix,
                                            const float* __restrict__ dwT,
                                            const float* __restrict__ og,
                                            const float* __restrict__ ob,
                                            __half* __restrict__ tbuf_h) {
    int gid = blockIdx.x * 256 + threadIdx.x;   // 4*9216*32
    int c = gid & 31;
    int p2 = gid >> 5;                          // bg*9216 + p
    int bg = p2 / N1, p = p2 - bg * N1;
    int b = bg >> 1, g = bg & 1;
    int oy = p / OW, ox = p - oy * OW;
    const float* qb = q_pix + ((size_t)b * HW) * 64 + g * 32 + c;
    float acc = 0.f;
#pragma unroll
    for (int dy = -1; dy <= 1; dy++) {
        int yy = oy + dy;
        if ((unsigned)yy >= (unsigned)OH) continue;
        float ysf = yy * RESZ;
        int y0 = min((int)ysf, 46);
        float wy = ysf - (float)y0;
#pragma unroll
        for (int dx = -1; dx <= 1; dx++) {
            int xx = ox + dx;
            if ((unsigned)xx >= (unsigned)OW) continue;
            float xsf = xx * RESZ;
            int x0 = min((int)xsf, 46);
            float wx = xsf - (float)x0;
            int i00 = (y0 * 48 + x0) * 64;
            float q00 = qb[i00], q01 = qb[i00 + 64];
            float q10 = qb[i00 + 48 * 64], q11 = qb[i00 + 49 * 64];
            float qv = (q00 * (1.f - wy) + q10 * wy) * (1.f - wx)
                     + (q01 * (1.f - wy) + q11 * wy) * wx;
            acc += qv * dwT[((dy + 1) * 3 + dx + 1) * 32 + c];
        }
    }
    float s = acc;
#pragma unroll
    for (int off = 1; off < 32; off <<= 1) s += __shfl_xor(s, off);
    float mu = s * (1.f / 32.f);
    float d = acc - mu;
    float v = d * d;
#pragma unroll
    for (int off = 1; off < 32; off <<= 1) v += __shfl_xor(v, off);
    float rsv = rsqrtf(v * (1.f / 32.f) + 1e-5f);
    float t = d * rsv * og[c] + ob[c];
    float ge = 0.5f * t * (1.f + erff(t * 0.70710678118654752f));
    tbuf_h[(size_t)p2 * 32 + c] = __float2half(ge);
}

// ---------------- K4: conv 3x3 32->18 + bias.
// Grid: 4 bg x 144 tiles (8x8 px) = 576 blocks x 512 threads (8 waves).
// Stage 10x10 halo x 32ch (fp16 -> f32) in LDS pitch 33.
// Wave w owns oc-group {3,3,2,2,2,2,2,2}; lane = pixel; wave-uniform weights from wg2.
__global__ __launch_bounds__(512) void k4_pred(const __half* __restrict__ tbuf_h,
                                               const float* __restrict__ wg2,
                                               const float* __restrict__ bsg2,
                                               float* __restrict__ pred) {
    int blk = blockIdx.x;
    int bg = blk / 144, tile = blk - bg * 144;
    int ty0 = (tile / 12) * 8, tx0 = (tile % 12) * 8;
    int tid = threadIdx.x;
    __shared__ float ts[100 * 33];   // [halo point][ic], pitch 33

    const __half* tb = tbuf_h + (size_t)bg * N1 * 32;
    for (int item = tid; item < 400; item += 512) {
        int pt = item >> 2, qg = item & 3;       // 8 channels per item
        int hy = ty0 + pt / 10 - 1;
        int hx = tx0 + pt % 10 - 1;
        float4 raw = make_float4(0.f, 0.f, 0.f, 0.f);
        if ((unsigned)hy < (unsigned)OH && (unsigned)hx < (unsigned)OW)
            raw = *(const float4*)(tb + ((size_t)(hy * OW + hx)) * 32 + qg * 8);
        const __half2* h2 = (const __half2*)&raw;
        int base = pt * 33 + qg * 8;
#pragma unroll
        for (int i = 0; i < 4; i++) {
            float2 f = __half22float2(h2[i]);
            ts[base + i * 2] = f.x;
            ts[base + i * 2 + 1] = f.y;
        }
    }
    __syncthreads();

    int w = __builtin_amdgcn_readfirstlane(tid >> 6);
    int lane = tid & 63;
    int y = lane >> 3, x = lane & 7;
    int ocb = ocb8(w), cnt = cnt8(w);
    float acc[3];
#pragma unroll
    for (int j = 0; j < 3; j++) acc[j] = bsg2[w * 3 + j];
    const float* tsb = &ts[(y * 10 + x) * 33];
    const float* wgp = wg2 + (size_t)w * 864;
    const int kof[9] = {0, 33, 66, 330, 363, 396, 660, 693, 726};
    for (int ic = 0; ic < 32; ic++) {
#pragma unroll
        for (int k = 0; k < 9; k++) {
            float tv = tsb[kof[k] + ic];
            const float* wr = wgp + (ic * 9 + k) * 3;
#pragma unroll
            for (int j = 0; j < 3; j++) acc[j] += tv * wr[j];
        }
    }
    int p = (ty0 + y) * OW + tx0 + x;
    float* pp = pred + ((size_t)bg * N1 + p) * 18 + ocb;
#pragma unroll
    for (int j = 0; j < 3; j++)
        if (j < cnt) pp[j] = acc[j];
}

// ---------------- K5: deformable attention. 1 wave = 4 consecutive pixels (same row);
// block = 16 pixels. Phase-separated px processing for deep VMEM pipelining.
__global__ __launch_bounds__(256) void k5_attn(const float* __restrict__ pred,
                                               const float* __restrict__ q_pix,
                                               const float* __restrict__ k_nhwc,
                                               const float* __restrict__ v_nhwc,
                                               const float* __restrict__ rpb,
                                               float* __restrict__ out) {
    int tid = threadIdx.x;
    int wv = __builtin_amdgcn_readfirstlane(tid >> 6);
    int lane = tid & 63;
    int gp = blockIdx.x * 16;              // block-base pixel (same bg, same row)
    int bg = gp / N1, p0 = gp % N1;
    int b = bg >> 1, g = bg & 1;
    int pw = p0 + wv * 4;                  // wave-base pixel
    int oy = pw / OW, ox0 = pw % OW;

    __shared__ float4 wts[4][4][9];        // [wave][px][tap] corner weights
    __shared__ int4   cof[4][4][9];        // [wave][px][tap] corner pixel offsets
    __shared__ float  outb[4][4][128];     // [wave][px][ch]

    // --- tap setup: lanes 0..35 -> (px, j)
    if (lane < 36) {
        int px = lane / 9, j = lane % 9;
        int p = pw + px;
        int ky = j / 3, kx = j % 3;
        const float* pp = pred + ((size_t)bg * N1 + p) * 18;
        float pr0 = pp[j * 2];
        float pr1 = pp[j * 2 + 1];
        float th0 = 1.f - 2.f * __builtin_amdgcn_rcpf(__expf(2.f * pr0) + 1.f);
        float th1 = 1.f - 2.f * __builtin_amdgcn_rcpf(__expf(2.f * pr1) + 1.f);
        float py  = th0 * 11.0f + (float)(ky - 1) + (float)oy;
        float pxc = th1 * 11.0f + (float)(kx - 1) + (float)(ox0 + px);
        float iy = py * RESZ, ix = pxc * RESZ;
        float y0f = floorf(iy), x0f = floorf(ix);
        float wy = iy - y0f, wx = ix - x0f;
        int y0 = (int)y0f, x0 = (int)x0f;
        bool vy0 = (unsigned)y0 < 48u, vy1 = (unsigned)(y0 + 1) < 48u;
        bool vx0 = (unsigned)x0 < 48u, vx1 = (unsigned)(x0 + 1) < 48u;
        int y0c = min(max(y0, 0), 47), y1c = min(max(y0 + 1, 0), 47);
        int x0c = min(max(x0, 0), 47), x1c = min(max(x0 + 1, 0), 47);
        float4 w;
        w.x = (vy0 && vx0) ? (1.f - wy) * (1.f - wx) : 0.f;
        w.y = (vy0 && vx1) ? (1.f - wy) * wx : 0.f;
        w.z = (vy1 && vx0) ? wy * (1.f - wx) : 0.f;
        w.w = (vy1 && vx1) ? wy * wx : 0.f;
        wts[wv][px][j] = w;
        cof[wv][px][j] = make_int4(y0c * 48 + x0c, y0c * 48 + x1c,
                                   y1c * 48 + x0c, y1c * 48 + x1c);
    }
    __syncthreads();

    int c = lane & 31, h = lane >> 5;
    int c4 = (lane & 31) * 4;
    const float* kb = k_nhwc + (size_t)bg * HW * 32;
    const float* rb = rpb + (size_t)g * 288;
    const float* qb = q_pix + (size_t)b * HW * 64 + g * 32 + c;
    const float* vbase = v_nhwc + (size_t)bg * HW * 128;

    float ysf = oy * RESZ;
    int qy0 = min((int)ysf, 46);
    float qwy = ysf - (float)qy0;

    // rpb values for this lane's taps (px-independent)
    float rv[5];
#pragma unroll
    for (int jj = 0; jj < 5; jj++) {
        int j = jj * 2 + h;
        rv[jj] = (j < 9) ? rb[j * 32 + c] : 0.f;
    }

    // --- qv for all 4 px
    float qv[4];
#pragma unroll
    for (int px = 0; px < 4; px++) {
        float xsf = (ox0 + px) * RESZ;
        int qx0 = min((int)xsf, 46);
        float qwx = xsf - (float)qx0;
        int qi = (qy0 * 48 + qx0) * 64;
        float q00 = qb[qi], q01 = qb[qi + 64];
        float q10 = qb[qi + 48 * 64], q11 = qb[qi + 49 * 64];
        qv[px] = ((q00 * (1.f - qwy) + q10 * qwy) * (1.f - qwx)
                + (q01 * (1.f - qwy) + q11 * qwy) * qwx) * SCALE_ATTN;
    }

    // --- scores for all 4 px (h-split taps)
    float s[4][5];
#pragma unroll
    for (int px = 0; px < 4; px++) {
#pragma unroll
        for (int jj = 0; jj < 5; jj++) {
            int j = jj * 2 + h;
            float partial = 0.f;
            if (j < 9) {
                float4 w = wts[wv][px][j];
                int4 co = cof[wv][px][j];
                float kv = w.x * kb[co.x * 32 + c] + w.y * kb[co.y * 32 + c]
                         + w.z * kb[co.z * 32 + c] + w.w * kb[co.w * 32 + c];
                partial = qv[px] * (kv + rv[jj]);
            }
#pragma unroll
            for (int off = 1; off < 32; off <<= 1) partial += __shfl_xor(partial, off);
            s[px][jj] = (j < 9) ? partial : -1e30f;
        }
    }

    // --- softmax per px (in-register); s becomes probabilities
#pragma unroll
    for (int px = 0; px < 4; px++) {
        float m = s[px][0];
#pragma unroll
        for (int jj = 1; jj < 5; jj++) m = fmaxf(m, s[px][jj]);
        m = fmaxf(m, __shfl_xor(m, 32));
        float e[5];
        float sum = 0.f;
#pragma unroll
        for (int jj = 0; jj < 5; jj++) { e[jj] = __expf(s[px][jj] - m); sum += e[jj]; }
        sum += __shfl_xor(sum, 32);
        float inv = __builtin_amdgcn_rcpf(sum);
#pragma unroll
        for (int jj = 0; jj < 5; jj++) s[px][jj] = e[jj] * inv;
    }

    // --- value phase: all px unrolled -> up to 80 independent float4 gathers
    float4 acc[4];
#pragma unroll
    for (int px = 0; px < 4; px++) acc[px] = make_float4(0.f, 0.f, 0.f, 0.f);
#pragma unroll
    for (int px = 0; px < 4; px++) {
#pragma unroll
        for (int jj = 0; jj < 5; jj++) {
            int j = jj * 2 + h;
            if (j < 9) {
                float pj = s[px][jj];
                float4 w = wts[wv][px][j];
                int4 co = cof[wv][px][j];
                float4 a0 = *(const float4*)(vbase + (size_t)co.x * 128 + c4);
                float4 a1 = *(const float4*)(vbase + (size_t)co.y * 128 + c4);
                float4 a2 = *(const float4*)(vbase + (size_t)co.z * 128 + c4);
                float4 a3 = *(const float4*)(vbase + (size_t)co.w * 128 + c4);
                float f0 = w.x * pj, f1 = w.y * pj, f2 = w.z * pj, f3 = w.w * pj;
                acc[px].x += f0 * a0.x + f1 * a1.x + f2 * a2.x + f3 * a3.x;
                acc[px].y += f0 * a0.y + f1 * a1.y + f2 * a2.y + f3 * a3.y;
                acc[px].z += f0 * a0.z + f1 * a1.z + f2 * a2.z + f3 * a3.z;
                acc[px].w += f0 * a0.w + f1 * a1.w + f2 * a2.w + f3 * a3.w;
            }
        }
    }
#pragma unroll
    for (int px = 0; px < 4; px++) {
        acc[px].x += __shfl_xor(acc[px].x, 32);
        acc[px].y += __shfl_xor(acc[px].y, 32);
        acc[px].z += __shfl_xor(acc[px].z, 32);
        acc[px].w += __shfl_xor(acc[px].w, 32);
        if (lane < 32) *(float4*)&outb[wv][px][c4] = acc[px];
    }
    __syncthreads();

    // final write: thread ch<128 writes 4x float4 = 64B contiguous per channel
    if (tid < 128) {
        int ch = tid;
        float* op = out + ((size_t)b * NC + g * 128 + ch) * N1 + p0;
#pragma unroll
        for (int w2 = 0; w2 < 4; w2++) {
            float4 v4 = make_float4(outb[w2][0][ch], outb[w2][1][ch],
                                    outb[w2][2][ch], outb[w2][3][ch]);
            *(float4*)(op + w2 * 4) = v4;
        }
    }
}

extern "C" void kernel_launch(void* const* d_in, const int* in_sizes, int n_in,
                              void* d_out, int out_size, void* d_ws, size_t ws_size,
                              hipStream_t stream) {
    const float* x      = (const float*)d_in[0];
    const float* ln_g   = (const float*)d_in[1];
    const float* ln_b   = (const float*)d_in[2];
    const float* Wq     = (const float*)d_in[3];
    const float* Wk     = (const float*)d_in[4];
    const float* dw_w   = (const float*)d_in[5];
    const float* off_g  = (const float*)d_in[6];
    const float* off_bt = (const float*)d_in[7];
    const float* off_w  = (const float*)d_in[8];
    const float* off_b  = (const float*)d_in[9];
    const float* rpb    = (const float*)d_in[10];
    float* out = (float*)d_out;

    // Workspace layout. Total = 3,062,840 float-equivalents = 11.68 MB. NO aliasing.
    float* ws = (float*)d_ws;
    float* v_nhwc = ws;                       // 1179648 [4][2304][128]
    float* WT4    = v_nhwc + 1179648;         // 32768   [64][128][4]
    float* k_nhwc = WT4 + 32768;              // 294912  [4][2304][32]
    float* q_pix  = k_nhwc + 294912;          // 294912  [2][2304][64]
    float* pred   = q_pix + 294912;           // 663552  [4][9216][18]
    float* dwT    = pred + 663552;            // 288     [9][32]
    float* wg2    = dwT + 288;                // 6912    [8][288][3]
    float* bsg2   = wg2 + 6912;               // 24      [8][3]
    __half* tbuf_h = (__half*)(bsg2 + 24);    // 1179648 halves [4][9216][32]

    kA_prep<<<1309, 256, 0, stream>>>(x, Wq, Wk, off_w, dw_w, off_b,
                                      v_nhwc, WT4, dwT, wg2, bsg2);
    k1_ln_qk<<<1152, 256, 0, stream>>>(v_nhwc, ln_g, ln_b, WT4, q_pix, k_nhwc);
    k3_t<<<4608, 256, 0, stream>>>(q_pix, dwT, off_g, off_bt, tbuf_h);
    k4_pred<<<576, 512, 0, stream>>>(tbuf_h, wg2, bsg2, pred);
    k5_attn<<<2304, 256, 0, stream>>>(pred, q_pix, k_nhwc, v_nhwc, rpb, out);
}

// Round 12
// 163.945 us; speedup vs baseline: 1.1289x; 1.0170x over previous
//
#include <hip/hip_runtime.h>
#include <hip/hip_fp16.h>
#include <cstdint>
#include <cmath>

// Problem constants
#define NB 2
#define NC 256
#define HW 2304          // 48*48
#define HID 64
#define OH 96
#define OW 96
#define N1 9216          // 96*96
#define SCALE_ATTN 0.17677669529663689f   // 32^-0.5
#define RESZ ((float)(47.0/95.0))

// oc-group split for k4: 8 waves, counts {3,3,2,2,2,2,2,2}
__device__ __host__ inline int ocb8(int w) { return w < 2 ? 3 * w : 6 + 2 * (w - 2); }
__device__ __host__ inline int cnt8(int w) { return w < 2 ? 3 : 2; }

struct h4v { __half2 lo, hi; };   // 4 halves = 8B

// ---------------- KA: fused prep.
// blk<1152: x NCHW -> v_nhwc fp16 [4][2304][128] (LDS-tiled transpose).
// else: WT4[c4][128][4]; dwT[tap][32]; wg2[8][288][3] (zero-padded); bsg2[24]
__global__ void kA_prep(const float* __restrict__ x, const float* __restrict__ Wq,
                        const float* __restrict__ Wk, const float* __restrict__ off_w,
                        const float* __restrict__ dw_w, const float* __restrict__ off_b,
                        __half* __restrict__ v_nhwc, float* __restrict__ WT4,
                        float* __restrict__ dwT, float* __restrict__ wg2,
                        float* __restrict__ bsg2) {
    int blk = blockIdx.x;
    if (blk < 1152) {
        int pt = blk % 72;
        int t2 = blk / 72;
        int ct = t2 & 3;
        int bg = t2 >> 2;
        int b = bg >> 1, g = bg & 1;
        __shared__ float tile[32][33];
        int tx = threadIdx.x & 31, row = threadIdx.x >> 5;   // row 0..7
#pragma unroll
        for (int r = 0; r < 4; r++) {
            int c = ct * 32 + row + r * 8;
            tile[row + r * 8][tx] = x[((size_t)(b * 256 + g * 128 + c)) * HW + pt * 32 + tx];
        }
        __syncthreads();
#pragma unroll
        for (int r = 0; r < 4; r++) {
            int p = pt * 32 + row + r * 8;
            v_nhwc[((size_t)bg * HW + p) * 128 + ct * 32 + tx] =
                __float2half(tile[tx][row + r * 8]);
        }
    } else {
        int idx = (blk - 1152) * 256 + threadIdx.x;
        if (idx < 32768) {
            int c = idx >> 7, t = idx & 127;
            float v = (t < 64) ? Wq[t * 256 + c] : Wk[(t - 64) * 256 + c];
            WT4[(((size_t)(c >> 2) * 128) + t) * 4 + (c & 3)] = v;
        } else if (idx < 32768 + 288) {
            int i = idx - 32768;
            int wi = i >> 5, c = i & 31;
            dwT[i] = dw_w[c * 9 + wi];
        } else if (idx < 32768 + 288 + 8 * 288 * 3) {
            int i = idx - (32768 + 288);
            int w = i / 864, r = i - w * 864;
            int kk = r / 3, j = r - kk * 3;
            wg2[i] = (j < cnt8(w)) ? off_w[(ocb8(w) + j) * 288 + kk] : 0.f;
        } else if (idx < 32768 + 288 + 8 * 288 * 3 + 24) {
            int i = idx - (32768 + 288 + 8 * 288 * 3);
            int w = i / 3, j = i - w * 3;
            bsg2[i] = (j < cnt8(w)) ? off_b[ocb8(w) + j] : 0.f;
        }
    }
}

// ---------------- K1: channel LN over 256 + Q/K projection, reading coalesced v_nhwc.
__global__ __launch_bounds__(256) void k1_ln_qk(const __half* __restrict__ v_nhwc,
                         const float* __restrict__ ln_g, const float* __restrict__ ln_b,
                         const float* __restrict__ WT4,
                         float* __restrict__ q_pix, __half* __restrict__ k_nhwc) {
    int blk = blockIdx.x;            // 0..1151
    int tid = threadIdx.x;
    int wv = tid >> 6, lane = tid & 63;
    __shared__ float xs[4][256];
    {
        int pix = blk * 4 + wv;
        int b = pix / HW, p = pix - b * HW;
        int c0 = lane * 2;
        __half2 h0 = *(const __half2*)(v_nhwc + (((size_t)(b * 2 + 0) * HW) + p) * 128 + c0);
        __half2 h1 = *(const __half2*)(v_nhwc + (((size_t)(b * 2 + 1) * HW) + p) * 128 + c0);
        float2 u0 = __half22float2(h0);
        float2 u1 = __half22float2(h1);
        float s = u0.x + u0.y + u1.x + u1.y;
#pragma unroll
        for (int off = 1; off < 64; off <<= 1) s += __shfl_xor(s, off);
        float mu = s * (1.f / 256.f);
        float d0 = u0.x - mu, d1 = u0.y - mu, d2 = u1.x - mu, d3 = u1.y - mu;
        float q = d0 * d0 + d1 * d1 + d2 * d2 + d3 * d3;
#pragma unroll
        for (int off = 1; off < 64; off <<= 1) q += __shfl_xor(q, off);
        float rs = rsqrtf(q * (1.f / 256.f) + 1e-5f);
        float2 w0, w1;
        w0.x = d0 * rs * ln_g[c0] + ln_b[c0];
        w0.y = d1 * rs * ln_g[c0 + 1] + ln_b[c0 + 1];
        w1.x = d2 * rs * ln_g[128 + c0] + ln_b[128 + c0];
        w1.y = d3 * rs * ln_g[129 + c0] + ln_b[129 + c0];
        *(float2*)&xs[wv][c0] = w0;
        *(float2*)&xs[wv][128 + c0] = w1;
    }
    __syncthreads();
    int o = tid & 127, ph = tid >> 7;
    float a0 = 0.f, a1 = 0.f;
    const float4* wp = (const float4*)WT4 + o;         // stride 128 float4s per c4
    const float4* xa = (const float4*)xs[ph * 2];
    const float4* xb4 = (const float4*)xs[ph * 2 + 1];
#pragma unroll 8
    for (int c4 = 0; c4 < 64; c4++) {
        float4 w = wp[(size_t)c4 * 128];
        float4 p0 = xa[c4], p1 = xb4[c4];
        a0 += w.x * p0.x + w.y * p0.y + w.z * p0.z + w.w * p0.w;
        a1 += w.x * p1.x + w.y * p1.y + w.z * p1.z + w.w * p1.w;
    }
#pragma unroll
    for (int k = 0; k < 2; k++) {
        int pix = blk * 4 + ph * 2 + k;
        int b = pix / HW, p = pix - b * HW;
        float a = k ? a1 : a0;
        if (o < 64) {
            q_pix[(((size_t)b * HW) + p) * 64 + o] = a;
        } else {
            int t = o - 64, g = t >> 5, c32 = t & 31;
            k_nhwc[(((size_t)(b * 2 + g) * HW) + p) * 32 + c32] = __float2half(a);
        }
    }
}

// ---------------- K3: t = GELU(LN(dw3x3(resize(q)))). Thread per (bg, pixel, ch).
__global__ __launch_bounds__(256) void k3_t(const float* __restrict__ q_pix,
                                            const float* __restrict__ dwT,
                                            const float* __restrict__ og,
                                            const float* __restrict__ ob,
                                            __half* __restrict__ tbuf_h) {
    int gid = blockIdx.x * 256 + threadIdx.x;   // 4*9216*32
    int c = gid & 31;
    int p2 = gid >> 5;                          // bg*9216 + p
    int bg = p2 / N1, p = p2 - bg * N1;
    int b = bg >> 1, g = bg & 1;
    int oy = p / OW, ox = p - oy * OW;
    const float* qb = q_pix + ((size_t)b * HW) * 64 + g * 32 + c;
    float acc = 0.f;
#pragma unroll
    for (int dy = -1; dy <= 1; dy++) {
        int yy = oy + dy;
        if ((unsigned)yy >= (unsigned)OH) continue;
        float ysf = yy * RESZ;
        int y0 = min((int)ysf, 46);
        float wy = ysf - (float)y0;
#pragma unroll
        for (int dx = -1; dx <= 1; dx++) {
            int xx = ox + dx;
            if ((unsigned)xx >= (unsigned)OW) continue;
            float xsf = xx * RESZ;
            int x0 = min((int)xsf, 46);
            float wx = xsf - (float)x0;
            int i00 = (y0 * 48 + x0) * 64;
            float q00 = qb[i00], q01 = qb[i00 + 64];
            float q10 = qb[i00 + 48 * 64], q11 = qb[i00 + 49 * 64];
            float qv = (q00 * (1.f - wy) + q10 * wy) * (1.f - wx)
                     + (q01 * (1.f - wy) + q11 * wy) * wx;
            acc += qv * dwT[((dy + 1) * 3 + dx + 1) * 32 + c];
        }
    }
    float s = acc;
#pragma unroll
    for (int off = 1; off < 32; off <<= 1) s += __shfl_xor(s, off);
    float mu = s * (1.f / 32.f);
    float d = acc - mu;
    float v = d * d;
#pragma unroll
    for (int off = 1; off < 32; off <<= 1) v += __shfl_xor(v, off);
    float rsv = rsqrtf(v * (1.f / 32.f) + 1e-5f);
    float t = d * rsv * og[c] + ob[c];
    float ge = 0.5f * t * (1.f + erff(t * 0.70710678118654752f));
    tbuf_h[(size_t)p2 * 32 + c] = __float2half(ge);
}

// ---------------- K4: conv 3x3 32->18 + bias.
// 576 blocks x 512 threads (8 waves). 10x10 halo x 32ch (fp16 -> f32) in LDS pitch 33.
__global__ __launch_bounds__(512) void k4_pred(const __half* __restrict__ tbuf_h,
                                               const float* __restrict__ wg2,
                                               const float* __restrict__ bsg2,
                                               float* __restrict__ pred) {
    int blk = blockIdx.x;
    int bg = blk / 144, tile = blk - bg * 144;
    int ty0 = (tile / 12) * 8, tx0 = (tile % 12) * 8;
    int tid = threadIdx.x;
    __shared__ float ts[100 * 33];   // [halo point][ic], pitch 33

    const __half* tb = tbuf_h + (size_t)bg * N1 * 32;
    for (int item = tid; item < 400; item += 512) {
        int pt = item >> 2, qg = item & 3;       // 8 channels per item
        int hy = ty0 + pt / 10 - 1;
        int hx = tx0 + pt % 10 - 1;
        float4 raw = make_float4(0.f, 0.f, 0.f, 0.f);
        if ((unsigned)hy < (unsigned)OH && (unsigned)hx < (unsigned)OW)
            raw = *(const float4*)(tb + ((size_t)(hy * OW + hx)) * 32 + qg * 8);
        const __half2* h2 = (const __half2*)&raw;
        int base = pt * 33 + qg * 8;
#pragma unroll
        for (int i = 0; i < 4; i++) {
            float2 f = __half22float2(h2[i]);
            ts[base + i * 2] = f.x;
            ts[base + i * 2 + 1] = f.y;
        }
    }
    __syncthreads();

    int w = __builtin_amdgcn_readfirstlane(tid >> 6);
    int lane = tid & 63;
    int y = lane >> 3, x = lane & 7;
    int ocb = ocb8(w), cnt = cnt8(w);
    float acc[3];
#pragma unroll
    for (int j = 0; j < 3; j++) acc[j] = bsg2[w * 3 + j];
    const float* tsb = &ts[(y * 10 + x) * 33];
    const float* wgp = wg2 + (size_t)w * 864;
    const int kof[9] = {0, 33, 66, 330, 363, 396, 660, 693, 726};
    for (int ic = 0; ic < 32; ic++) {
#pragma unroll
        for (int k = 0; k < 9; k++) {
            float tv = tsb[kof[k] + ic];
            const float* wr = wgp + (ic * 9 + k) * 3;
#pragma unroll
            for (int j = 0; j < 3; j++) acc[j] += tv * wr[j];
        }
    }
    int p = (ty0 + y) * OW + tx0 + x;
    float* pp = pred + ((size_t)bg * N1 + p) * 18 + ocb;
#pragma unroll
    for (int j = 0; j < 3; j++)
        if (j < cnt) pp[j] = acc[j];
}

// ---------------- K5: deformable attention. 1 wave = 4 consecutive pixels (same row);
// block = 16 pixels. fp16 K/V; packed __hfma2 v-accumulation.
__global__ __launch_bounds__(256) void k5_attn(const float* __restrict__ pred,
                                               const float* __restrict__ q_pix,
                                               const __half* __restrict__ k_nhwc,
                                               const __half* __restrict__ v_nhwc,
                                               const float* __restrict__ rpb,
                                               float* __restrict__ out) {
    int tid = threadIdx.x;
    int wv = __builtin_amdgcn_readfirstlane(tid >> 6);
    int lane = tid & 63;
    int gp = blockIdx.x * 16;              // block-base pixel (same bg, same row)
    int bg = gp / N1, p0 = gp % N1;
    int b = bg >> 1, g = bg & 1;
    int pw = p0 + wv * 4;                  // wave-base pixel
    int oy = pw / OW, ox0 = pw % OW;

    __shared__ float4 wts[4][4][9];        // [wave][px][tap] corner weights
    __shared__ int4   cof[4][4][9];        // [wave][px][tap] corner pixel offsets
    __shared__ float  outb[4][4][128];     // [wave][px][ch]

    // --- tap setup: lanes 0..35 -> (px, j)
    if (lane < 36) {
        int px = lane / 9, j = lane % 9;
        int p = pw + px;
        int ky = j / 3, kx = j % 3;
        const float* pp = pred + ((size_t)bg * N1 + p) * 18;
        float pr0 = pp[j * 2];
        float pr1 = pp[j * 2 + 1];
        float th0 = 1.f - 2.f * __builtin_amdgcn_rcpf(__expf(2.f * pr0) + 1.f);
        float th1 = 1.f - 2.f * __builtin_amdgcn_rcpf(__expf(2.f * pr1) + 1.f);
        float py  = th0 * 11.0f + (float)(ky - 1) + (float)oy;
        float pxc = th1 * 11.0f + (float)(kx - 1) + (float)(ox0 + px);
        float iy = py * RESZ, ix = pxc * RESZ;
        float y0f = floorf(iy), x0f = floorf(ix);
        float wy = iy - y0f, wx = ix - x0f;
        int y0 = (int)y0f, x0 = (int)x0f;
        bool vy0 = (unsigned)y0 < 48u, vy1 = (unsigned)(y0 + 1) < 48u;
        bool vx0 = (unsigned)x0 < 48u, vx1 = (unsigned)(x0 + 1) < 48u;
        int y0c = min(max(y0, 0), 47), y1c = min(max(y0 + 1, 0), 47);
        int x0c = min(max(x0, 0), 47), x1c = min(max(x0 + 1, 0), 47);
        float4 w;
        w.x = (vy0 && vx0) ? (1.f - wy) * (1.f - wx) : 0.f;
        w.y = (vy0 && vx1) ? (1.f - wy) * wx : 0.f;
        w.z = (vy1 && vx0) ? wy * (1.f - wx) : 0.f;
        w.w = (vy1 && vx1) ? wy * wx : 0.f;
        wts[wv][px][j] = w;
        cof[wv][px][j] = make_int4(y0c * 48 + x0c, y0c * 48 + x1c,
                                   y1c * 48 + x0c, y1c * 48 + x1c);
    }
    __syncthreads();

    int c = lane & 31, h = lane >> 5;
    int c4 = (lane & 31) * 4;
    const __half* kb = k_nhwc + (size_t)bg * HW * 32;
    const float* rb = rpb + (size_t)g * 288;
    const float* qb = q_pix + (size_t)b * HW * 64 + g * 32 + c;
    const __half* vb = v_nhwc + (size_t)bg * HW * 128 + c4;

    float ysf = oy * RESZ;
    int qy0 = min((int)ysf, 46);
    float qwy = ysf - (float)qy0;

    // rpb values for this lane's taps (px-independent)
    float rv[5];
#pragma unroll
    for (int jj = 0; jj < 5; jj++) {
        int j = jj * 2 + h;
        rv[jj] = (j < 9) ? rb[j * 32 + c] : 0.f;
    }

    // --- qv for all 4 px
    float qv[4];
#pragma unroll
    for (int px = 0; px < 4; px++) {
        float xsf = (ox0 + px) * RESZ;
        int qx0 = min((int)xsf, 46);
        float qwx = xsf - (float)qx0;
        int qi = (qy0 * 48 + qx0) * 64;
        float q00 = qb[qi], q01 = qb[qi + 64];
        float q10 = qb[qi + 48 * 64], q11 = qb[qi + 49 * 64];
        qv[px] = ((q00 * (1.f - qwy) + q10 * qwy) * (1.f - qwx)
                + (q01 * (1.f - qwy) + q11 * qwy) * qwx) * SCALE_ATTN;
    }

    // --- scores for all 4 px (h-split taps), fp16 k loads
    float s[4][5];
#pragma unroll
    for (int px = 0; px < 4; px++) {
#pragma unroll
        for (int jj = 0; jj < 5; jj++) {
            int j = jj * 2 + h;
            float partial = 0.f;
            if (j < 9) {
                float4 w = wts[wv][px][j];
                int4 co = cof[wv][px][j];
                float kv = w.x * __half2float(kb[co.x * 32 + c])
                         + w.y * __half2float(kb[co.y * 32 + c])
                         + w.z * __half2float(kb[co.z * 32 + c])
                         + w.w * __half2float(kb[co.w * 32 + c]);
                partial = qv[px] * (kv + rv[jj]);
            }
#pragma unroll
            for (int off = 1; off < 32; off <<= 1) partial += __shfl_xor(partial, off);
            s[px][jj] = (j < 9) ? partial : -1e30f;
        }
    }

    // --- softmax per px (in-register); s becomes probabilities
#pragma unroll
    for (int px = 0; px < 4; px++) {
        float m = s[px][0];
#pragma unroll
        for (int jj = 1; jj < 5; jj++) m = fmaxf(m, s[px][jj]);
        m = fmaxf(m, __shfl_xor(m, 32));
        float e[5];
        float sum = 0.f;
#pragma unroll
        for (int jj = 0; jj < 5; jj++) { e[jj] = __expf(s[px][jj] - m); sum += e[jj]; }
        sum += __shfl_xor(sum, 32);
        float inv = __builtin_amdgcn_rcpf(sum);
#pragma unroll
        for (int jj = 0; jj < 5; jj++) s[px][jj] = e[jj] * inv;
    }

    // --- value phase: fp16 loads (8B/lane), packed __hfma2 accumulation
    __half2 ac0[4], ac1[4];
#pragma unroll
    for (int px = 0; px < 4; px++) {
        ac0[px] = __float2half2_rn(0.f);
        ac1[px] = __float2half2_rn(0.f);
    }
#pragma unroll
    for (int px = 0; px < 4; px++) {
#pragma unroll
        for (int jj = 0; jj < 5; jj++) {
            int j = jj * 2 + h;
            if (j < 9) {
                float pj = s[px][jj];
                float4 w = wts[wv][px][j];
                int4 co = cof[wv][px][j];
                h4v a0 = *(const h4v*)(vb + (size_t)co.x * 128);
                h4v a1 = *(const h4v*)(vb + (size_t)co.y * 128);
                h4v a2 = *(const h4v*)(vb + (size_t)co.z * 128);
                h4v a3 = *(const h4v*)(vb + (size_t)co.w * 128);
                __half2 f0 = __float2half2_rn(w.x * pj);
                __half2 f1 = __float2half2_rn(w.y * pj);
                __half2 f2 = __float2half2_rn(w.z * pj);
                __half2 f3 = __float2half2_rn(w.w * pj);
                ac0[px] = __hfma2(f0, a0.lo, ac0[px]);
                ac1[px] = __hfma2(f0, a0.hi, ac1[px]);
                ac0[px] = __hfma2(f1, a1.lo, ac0[px]);
                ac1[px] = __hfma2(f1, a1.hi, ac1[px]);
                ac0[px] = __hfma2(f2, a2.lo, ac0[px]);
                ac1[px] = __hfma2(f2, a2.hi, ac1[px]);
                ac0[px] = __hfma2(f3, a3.lo, ac0[px]);
                ac1[px] = __hfma2(f3, a3.hi, ac1[px]);
            }
        }
    }
#pragma unroll
    for (int px = 0; px < 4; px++) {
        float2 lo = __half22float2(ac0[px]);
        float2 hi = __half22float2(ac1[px]);
        float4 acc = make_float4(lo.x, lo.y, hi.x, hi.y);
        acc.x += __shfl_xor(acc.x, 32);
        acc.y += __shfl_xor(acc.y, 32);
        acc.z += __shfl_xor(acc.z, 32);
        acc.w += __shfl_xor(acc.w, 32);
        if (lane < 32) *(float4*)&outb[wv][px][c4] = acc;
    }
    __syncthreads();

    // final write: thread ch<128 writes 4x float4 = 64B contiguous per channel
    if (tid < 128) {
        int ch = tid;
        float* op = out + ((size_t)b * NC + g * 128 + ch) * N1 + p0;
#pragma unroll
        for (int w2 = 0; w2 < 4; w2++) {
            float4 v4 = make_float4(outb[w2][0][ch], outb[w2][1][ch],
                                    outb[w2][2][ch], outb[w2][3][ch]);
            *(float4*)(op + w2 * 4) = v4;
        }
    }
}

extern "C" void kernel_launch(void* const* d_in, const int* in_sizes, int n_in,
                              void* d_out, int out_size, void* d_ws, size_t ws_size,
                              hipStream_t stream) {
    const float* x      = (const float*)d_in[0];
    const float* ln_g   = (const float*)d_in[1];
    const float* ln_b   = (const float*)d_in[2];
    const float* Wq     = (const float*)d_in[3];
    const float* Wk     = (const float*)d_in[4];
    const float* dw_w   = (const float*)d_in[5];
    const float* off_g  = (const float*)d_in[6];
    const float* off_bt = (const float*)d_in[7];
    const float* off_w  = (const float*)d_in[8];
    const float* off_b  = (const float*)d_in[9];
    const float* rpb    = (const float*)d_in[10];
    float* out = (float*)d_out;

    // Workspace layout. fp32 region then fp16 region. Total ≈ 8.87 MB. NO aliasing.
    float* ws = (float*)d_ws;
    float* WT4    = ws;                       // 32768   [64][128][4]
    float* q_pix  = WT4 + 32768;              // 294912  [2][2304][64]
    float* pred   = q_pix + 294912;           // 663552  [4][9216][18]
    float* dwT    = pred + 663552;            // 288     [9][32]
    float* wg2    = dwT + 288;                // 6912    [8][288][3]
    float* bsg2   = wg2 + 6912;               // 24      [8][3]
    __half* v_nhwc = (__half*)(bsg2 + 24);    // 1179648 h [4][2304][128]
    __half* k_nhwc = v_nhwc + 1179648;        // 294912 h  [4][2304][32]
    __half* tbuf_h = k_nhwc + 294912;         // 1179648 h [4][9216][32]

    kA_prep<<<1309, 256, 0, stream>>>(x, Wq, Wk, off_w, dw_w, off_b,
                                      v_nhwc, WT4, dwT, wg2, bsg2);
    k1_ln_qk<<<1152, 256, 0, stream>>>(v_nhwc, ln_g, ln_b, WT4, q_pix, k_nhwc);
    k3_t<<<4608, 256, 0, stream>>>(q_pix, dwT, off_g, off_bt, tbuf_h);
    k4_pred<<<576, 512, 0, stream>>>(tbuf_h, wg2, bsg2, pred);
    k5_attn<<<2304, 256, 0, stream>>>(pred, q_pix, k_nhwc, v_nhwc, rpb, out);
}

// Round 13
// 163.215 us; speedup vs baseline: 1.1340x; 1.0045x over previous
//
#include <hip/hip_runtime.h>
#include <hip/hip_fp16.h>
#include <cstdint>
#include <cmath>

// Problem constants
#define NB 2
#define NC 256
#define HW 2304          // 48*48
#define HID 64
#define OH 96
#define OW 96
#define N1 9216          // 96*96
#define SCALE_ATTN 0.17677669529663689f   // 32^-0.5
#define RESZ ((float)(47.0/95.0))

// oc-group split for k4: 8 waves, counts {3,3,2,2,2,2,2,2}
__device__ __host__ inline int ocb8(int w) { return w < 2 ? 3 * w : 6 + 2 * (w - 2); }
__device__ __host__ inline int cnt8(int w) { return w < 2 ? 3 : 2; }

struct h4v { __half2 lo, hi; };   // 4 halves = 8B

// ---------------- KA: fused prep.
// blk<1152: x NCHW -> v_nhwc fp16 [4][2304][128] (LDS-tiled transpose).
// else: WT4[c4][128][4]; dwT[tap][32]; wg2[8][288][3] (zero-padded); bsg2[24]
__global__ void kA_prep(const float* __restrict__ x, const float* __restrict__ Wq,
                        const float* __restrict__ Wk, const float* __restrict__ off_w,
                        const float* __restrict__ dw_w, const float* __restrict__ off_b,
                        __half* __restrict__ v_nhwc, float* __restrict__ WT4,
                        float* __restrict__ dwT, float* __restrict__ wg2,
                        float* __restrict__ bsg2) {
    int blk = blockIdx.x;
    if (blk < 1152) {
        int pt = blk % 72;
        int t2 = blk / 72;
        int ct = t2 & 3;
        int bg = t2 >> 2;
        int b = bg >> 1, g = bg & 1;
        __shared__ float tile[32][33];
        int tx = threadIdx.x & 31, row = threadIdx.x >> 5;   // row 0..7
#pragma unroll
        for (int r = 0; r < 4; r++) {
            int c = ct * 32 + row + r * 8;
            tile[row + r * 8][tx] = x[((size_t)(b * 256 + g * 128 + c)) * HW + pt * 32 + tx];
        }
        __syncthreads();
#pragma unroll
        for (int r = 0; r < 4; r++) {
            int p = pt * 32 + row + r * 8;
            v_nhwc[((size_t)bg * HW + p) * 128 + ct * 32 + tx] =
                __float2half(tile[tx][row + r * 8]);
        }
    } else {
        int idx = (blk - 1152) * 256 + threadIdx.x;
        if (idx < 32768) {
            int c = idx >> 7, t = idx & 127;
            float v = (t < 64) ? Wq[t * 256 + c] : Wk[(t - 64) * 256 + c];
            WT4[(((size_t)(c >> 2) * 128) + t) * 4 + (c & 3)] = v;
        } else if (idx < 32768 + 288) {
            int i = idx - 32768;
            int wi = i >> 5, c = i & 31;
            dwT[i] = dw_w[c * 9 + wi];
        } else if (idx < 32768 + 288 + 8 * 288 * 3) {
            int i = idx - (32768 + 288);
            int w = i / 864, r = i - w * 864;
            int kk = r / 3, j = r - kk * 3;
            wg2[i] = (j < cnt8(w)) ? off_w[(ocb8(w) + j) * 288 + kk] : 0.f;
        } else if (idx < 32768 + 288 + 8 * 288 * 3 + 24) {
            int i = idx - (32768 + 288 + 8 * 288 * 3);
            int w = i / 3, j = i - w * 3;
            bsg2[i] = (j < cnt8(w)) ? off_b[ocb8(w) + j] : 0.f;
        }
    }
}

// ---------------- K1: channel LN over 256 + Q/K projection, reading coalesced v_nhwc.
// Block = 512 thr = 8 pixels (1 wave LN each); dot phase: o=tid&127, ph=tid>>7 (2 px each).
// One WT4 sweep (128KB) feeds 8 pixels.
__global__ __launch_bounds__(512) void k1_ln_qk(const __half* __restrict__ v_nhwc,
                         const float* __restrict__ ln_g, const float* __restrict__ ln_b,
                         const float* __restrict__ WT4,
                         float* __restrict__ q_pix, __half* __restrict__ k_nhwc) {
    int blk = blockIdx.x;            // 0..575
    int tid = threadIdx.x;
    int wv = tid >> 6, lane = tid & 63;
    __shared__ float xs[8][256];
    {
        int pix = blk * 8 + wv;
        int b = pix / HW, p = pix - b * HW;
        int c0 = lane * 2;
        __half2 h0 = *(const __half2*)(v_nhwc + (((size_t)(b * 2 + 0) * HW) + p) * 128 + c0);
        __half2 h1 = *(const __half2*)(v_nhwc + (((size_t)(b * 2 + 1) * HW) + p) * 128 + c0);
        float2 u0 = __half22float2(h0);
        float2 u1 = __half22float2(h1);
        float s = u0.x + u0.y + u1.x + u1.y;
#pragma unroll
        for (int off = 1; off < 64; off <<= 1) s += __shfl_xor(s, off);
        float mu = s * (1.f / 256.f);
        float d0 = u0.x - mu, d1 = u0.y - mu, d2 = u1.x - mu, d3 = u1.y - mu;
        float q = d0 * d0 + d1 * d1 + d2 * d2 + d3 * d3;
#pragma unroll
        for (int off = 1; off < 64; off <<= 1) q += __shfl_xor(q, off);
        float rs = rsqrtf(q * (1.f / 256.f) + 1e-5f);
        float2 w0, w1;
        w0.x = d0 * rs * ln_g[c0] + ln_b[c0];
        w0.y = d1 * rs * ln_g[c0 + 1] + ln_b[c0 + 1];
        w1.x = d2 * rs * ln_g[128 + c0] + ln_b[128 + c0];
        w1.y = d3 * rs * ln_g[129 + c0] + ln_b[129 + c0];
        *(float2*)&xs[wv][c0] = w0;
        *(float2*)&xs[wv][128 + c0] = w1;
    }
    __syncthreads();
    int o = tid & 127, ph = tid >> 7;     // ph 0..3, handles pixels 2ph, 2ph+1
    float a0 = 0.f, a1 = 0.f;
    const float4* wp = (const float4*)WT4 + o;         // stride 128 float4s per c4
    const float4* xa = (const float4*)xs[ph * 2];
    const float4* xb4 = (const float4*)xs[ph * 2 + 1];
#pragma unroll 8
    for (int c4 = 0; c4 < 64; c4++) {
        float4 w = wp[(size_t)c4 * 128];
        float4 p0 = xa[c4], p1 = xb4[c4];
        a0 += w.x * p0.x + w.y * p0.y + w.z * p0.z + w.w * p0.w;
        a1 += w.x * p1.x + w.y * p1.y + w.z * p1.z + w.w * p1.w;
    }
#pragma unroll
    for (int k = 0; k < 2; k++) {
        int pix = blk * 8 + ph * 2 + k;
        int b = pix / HW, p = pix - b * HW;
        float a = k ? a1 : a0;
        if (o < 64) {
            q_pix[(((size_t)b * HW) + p) * 64 + o] = a;
        } else {
            int t = o - 64, g = t >> 5, c32 = t & 31;
            k_nhwc[(((size_t)(b * 2 + g) * HW) + p) * 32 + c32] = __float2half(a);
        }
    }
}

// ---------------- K3: t = GELU(LN(dw3x3(resize(q)))). Thread per (bg, pixel, ch).
__global__ __launch_bounds__(256) void k3_t(const float* __restrict__ q_pix,
                                            const float* __restrict__ dwT,
                                            const float* __restrict__ og,
                                            const float* __restrict__ ob,
                                            __half* __restrict__ tbuf_h) {
    int gid = blockIdx.x * 256 + threadIdx.x;   // 4*9216*32
    int c = gid & 31;
    int p2 = gid >> 5;                          // bg*9216 + p
    int bg = p2 / N1, p = p2 - bg * N1;
    int b = bg >> 1, g = bg & 1;
    int oy = p / OW, ox = p - oy * OW;
    const float* qb = q_pix + ((size_t)b * HW) * 64 + g * 32 + c;
    float acc = 0.f;
#pragma unroll
    for (int dy = -1; dy <= 1; dy++) {
        int yy = oy + dy;
        if ((unsigned)yy >= (unsigned)OH) continue;
        float ysf = yy * RESZ;
        int y0 = min((int)ysf, 46);
        float wy = ysf - (float)y0;
#pragma unroll
        for (int dx = -1; dx <= 1; dx++) {
            int xx = ox + dx;
            if ((unsigned)xx >= (unsigned)OW) continue;
            float xsf = xx * RESZ;
            int x0 = min((int)xsf, 46);
            float wx = xsf - (float)x0;
            int i00 = (y0 * 48 + x0) * 64;
            float q00 = qb[i00], q01 = qb[i00 + 64];
            float q10 = qb[i00 + 48 * 64], q11 = qb[i00 + 49 * 64];
            float qv = (q00 * (1.f - wy) + q10 * wy) * (1.f - wx)
                     + (q01 * (1.f - wy) + q11 * wy) * wx;
            acc += qv * dwT[((dy + 1) * 3 + dx + 1) * 32 + c];
        }
    }
    float s = acc;
#pragma unroll
    for (int off = 1; off < 32; off <<= 1) s += __shfl_xor(s, off);
    float mu = s * (1.f / 32.f);
    float d = acc - mu;
    float v = d * d;
#pragma unroll
    for (int off = 1; off < 32; off <<= 1) v += __shfl_xor(v, off);
    float rsv = rsqrtf(v * (1.f / 32.f) + 1e-5f);
    float t = d * rsv * og[c] + ob[c];
    float ge = 0.5f * t * (1.f + erff(t * 0.70710678118654752f));
    tbuf_h[(size_t)p2 * 32 + c] = __float2half(ge);
}

// ---------------- K4: conv 3x3 32->18 + bias.
// 576 blocks x 512 threads (8 waves). 10x10 halo x 32ch (fp16 -> f32) in LDS pitch 33.
__global__ __launch_bounds__(512) void k4_pred(const __half* __restrict__ tbuf_h,
                                               const float* __restrict__ wg2,
                                               const float* __restrict__ bsg2,
                                               float* __restrict__ pred) {
    int blk = blockIdx.x;
    int bg = blk / 144, tile = blk - bg * 144;
    int ty0 = (tile / 12) * 8, tx0 = (tile % 12) * 8;
    int tid = threadIdx.x;
    __shared__ float ts[100 * 33];   // [halo point][ic], pitch 33

    const __half* tb = tbuf_h + (size_t)bg * N1 * 32;
    for (int item = tid; item < 400; item += 512) {
        int pt = item >> 2, qg = item & 3;       // 8 channels per item
        int hy = ty0 + pt / 10 - 1;
        int hx = tx0 + pt % 10 - 1;
        float4 raw = make_float4(0.f, 0.f, 0.f, 0.f);
        if ((unsigned)hy < (unsigned)OH && (unsigned)hx < (unsigned)OW)
            raw = *(const float4*)(tb + ((size_t)(hy * OW + hx)) * 32 + qg * 8);
        const __half2* h2 = (const __half2*)&raw;
        int base = pt * 33 + qg * 8;
#pragma unroll
        for (int i = 0; i < 4; i++) {
            float2 f = __half22float2(h2[i]);
            ts[base + i * 2] = f.x;
            ts[base + i * 2 + 1] = f.y;
        }
    }
    __syncthreads();

    int w = __builtin_amdgcn_readfirstlane(tid >> 6);
    int lane = tid & 63;
    int y = lane >> 3, x = lane & 7;
    int ocb = ocb8(w), cnt = cnt8(w);
    float acc[3];
#pragma unroll
    for (int j = 0; j < 3; j++) acc[j] = bsg2[w * 3 + j];
    const float* tsb = &ts[(y * 10 + x) * 33];
    const float* wgp = wg2 + (size_t)w * 864;
    const int kof[9] = {0, 33, 66, 330, 363, 396, 660, 693, 726};
    for (int ic = 0; ic < 32; ic++) {
#pragma unroll
        for (int k = 0; k < 9; k++) {
            float tv = tsb[kof[k] + ic];
            const float* wr = wgp + (ic * 9 + k) * 3;
#pragma unroll
            for (int j = 0; j < 3; j++) acc[j] += tv * wr[j];
        }
    }
    int p = (ty0 + y) * OW + tx0 + x;
    float* pp = pred + ((size_t)bg * N1 + p) * 18 + ocb;
#pragma unroll
    for (int j = 0; j < 3; j++)
        if (j < cnt) pp[j] = acc[j];
}

// ---------------- K5: deformable attention. 1 wave = 2 consecutive pixels (same row);
// block = 8 pixels (4 waves). fp16 K/V; packed __hfma2 v-accumulation.
__global__ __launch_bounds__(256) void k5_attn(const float* __restrict__ pred,
                                               const float* __restrict__ q_pix,
                                               const __half* __restrict__ k_nhwc,
                                               const __half* __restrict__ v_nhwc,
                                               const float* __restrict__ rpb,
                                               float* __restrict__ out) {
    int tid = threadIdx.x;
    int wv = __builtin_amdgcn_readfirstlane(tid >> 6);
    int lane = tid & 63;
    int gp = blockIdx.x * 8;               // block-base pixel (same bg, same row)
    int bg = gp / N1, p0 = gp % N1;
    int b = bg >> 1, g = bg & 1;
    int pw = p0 + wv * 2;                  // wave-base pixel
    int oy = pw / OW, ox0 = pw % OW;

    __shared__ float4 wts[4][2][9];        // [wave][px][tap] corner weights
    __shared__ int4   cof[4][2][9];        // [wave][px][tap] corner pixel offsets
    __shared__ float  outb[4][2][128];     // [wave][px][ch]

    // --- tap setup: lanes 0..17 -> (px, j)
    if (lane < 18) {
        int px = lane / 9, j = lane % 9;
        int p = pw + px;
        int ky = j / 3, kx = j % 3;
        const float* pp = pred + ((size_t)bg * N1 + p) * 18;
        float pr0 = pp[j * 2];
        float pr1 = pp[j * 2 + 1];
        float th0 = 1.f - 2.f * __builtin_amdgcn_rcpf(__expf(2.f * pr0) + 1.f);
        float th1 = 1.f - 2.f * __builtin_amdgcn_rcpf(__expf(2.f * pr1) + 1.f);
        float py  = th0 * 11.0f + (float)(ky - 1) + (float)oy;
        float pxc = th1 * 11.0f + (float)(kx - 1) + (float)(ox0 + px);
        float iy = py * RESZ, ix = pxc * RESZ;
        float y0f = floorf(iy), x0f = floorf(ix);
        float wy = iy - y0f, wx = ix - x0f;
        int y0 = (int)y0f, x0 = (int)x0f;
        bool vy0 = (unsigned)y0 < 48u, vy1 = (unsigned)(y0 + 1) < 48u;
        bool vx0 = (unsigned)x0 < 48u, vx1 = (unsigned)(x0 + 1) < 48u;
        int y0c = min(max(y0, 0), 47), y1c = min(max(y0 + 1, 0), 47);
        int x0c = min(max(x0, 0), 47), x1c = min(max(x0 + 1, 0), 47);
        float4 w;
        w.x = (vy0 && vx0) ? (1.f - wy) * (1.f - wx) : 0.f;
        w.y = (vy0 && vx1) ? (1.f - wy) * wx : 0.f;
        w.z = (vy1 && vx0) ? wy * (1.f - wx) : 0.f;
        w.w = (vy1 && vx1) ? wy * wx : 0.f;
        wts[wv][px][j] = w;
        cof[wv][px][j] = make_int4(y0c * 48 + x0c, y0c * 48 + x1c,
                                   y1c * 48 + x0c, y1c * 48 + x1c);
    }
    __syncthreads();

    int c = lane & 31, h = lane >> 5;
    int c4 = (lane & 31) * 4;
    const __half* kb = k_nhwc + (size_t)bg * HW * 32;
    const float* rb = rpb + (size_t)g * 288;
    const float* qb = q_pix + (size_t)b * HW * 64 + g * 32 + c;
    const __half* vb = v_nhwc + (size_t)bg * HW * 128 + c4;

    float ysf = oy * RESZ;
    int qy0 = min((int)ysf, 46);
    float qwy = ysf - (float)qy0;

    // rpb values for this lane's taps (px-independent)
    float rv[5];
#pragma unroll
    for (int jj = 0; jj < 5; jj++) {
        int j = jj * 2 + h;
        rv[jj] = (j < 9) ? rb[j * 32 + c] : 0.f;
    }

    // --- qv for both px
    float qv[2];
#pragma unroll
    for (int px = 0; px < 2; px++) {
        float xsf = (ox0 + px) * RESZ;
        int qx0 = min((int)xsf, 46);
        float qwx = xsf - (float)qx0;
        int qi = (qy0 * 48 + qx0) * 64;
        float q00 = qb[qi], q01 = qb[qi + 64];
        float q10 = qb[qi + 48 * 64], q11 = qb[qi + 49 * 64];
        qv[px] = ((q00 * (1.f - qwy) + q10 * qwy) * (1.f - qwx)
                + (q01 * (1.f - qwy) + q11 * qwy) * qwx) * SCALE_ATTN;
    }

    // --- scores for both px (h-split taps), fp16 k loads
    float s[2][5];
#pragma unroll
    for (int px = 0; px < 2; px++) {
#pragma unroll
        for (int jj = 0; jj < 5; jj++) {
            int j = jj * 2 + h;
            float partial = 0.f;
            if (j < 9) {
                float4 w = wts[wv][px][j];
                int4 co = cof[wv][px][j];
                float kv = w.x * __half2float(kb[co.x * 32 + c])
                         + w.y * __half2float(kb[co.y * 32 + c])
                         + w.z * __half2float(kb[co.z * 32 + c])
                         + w.w * __half2float(kb[co.w * 32 + c]);
                partial = qv[px] * (kv + rv[jj]);
            }
#pragma unroll
            for (int off = 1; off < 32; off <<= 1) partial += __shfl_xor(partial, off);
            s[px][jj] = (j < 9) ? partial : -1e30f;
        }
    }

    // --- softmax per px (in-register); s becomes probabilities
#pragma unroll
    for (int px = 0; px < 2; px++) {
        float m = s[px][0];
#pragma unroll
        for (int jj = 1; jj < 5; jj++) m = fmaxf(m, s[px][jj]);
        m = fmaxf(m, __shfl_xor(m, 32));
        float e[5];
        float sum = 0.f;
#pragma unroll
        for (int jj = 0; jj < 5; jj++) { e[jj] = __expf(s[px][jj] - m); sum += e[jj]; }
        sum += __shfl_xor(sum, 32);
        float inv = __builtin_amdgcn_rcpf(sum);
#pragma unroll
        for (int jj = 0; jj < 5; jj++) s[px][jj] = e[jj] * inv;
    }

    // --- value phase: fp16 loads (8B/lane), packed __hfma2 accumulation
    __half2 ac0[2], ac1[2];
#pragma unroll
    for (int px = 0; px < 2; px++) {
        ac0[px] = __float2half2_rn(0.f);
        ac1[px] = __float2half2_rn(0.f);
    }
#pragma unroll
    for (int px = 0; px < 2; px++) {
#pragma unroll
        for (int jj = 0; jj < 5; jj++) {
            int j = jj * 2 + h;
            if (j < 9) {
                float pj = s[px][jj];
                float4 w = wts[wv][px][j];
                int4 co = cof[wv][px][j];
                h4v a0 = *(const h4v*)(vb + (size_t)co.x * 128);
                h4v a1 = *(const h4v*)(vb + (size_t)co.y * 128);
                h4v a2 = *(const h4v*)(vb + (size_t)co.z * 128);
                h4v a3 = *(const h4v*)(vb + (size_t)co.w * 128);
                __half2 f0 = __float2half2_rn(w.x * pj);
                __half2 f1 = __float2half2_rn(w.y * pj);
                __half2 f2 = __float2half2_rn(w.z * pj);
                __half2 f3 = __float2half2_rn(w.w * pj);
                ac0[px] = __hfma2(f0, a0.lo, ac0[px]);
                ac1[px] = __hfma2(f0, a0.hi, ac1[px]);
                ac0[px] = __hfma2(f1, a1.lo, ac0[px]);
                ac1[px] = __hfma2(f1, a1.hi, ac1[px]);
                ac0[px] = __hfma2(f2, a2.lo, ac0[px]);
                ac1[px] = __hfma2(f2, a2.hi, ac1[px]);
                ac0[px] = __hfma2(f3, a3.lo, ac0[px]);
                ac1[px] = __hfma2(f3, a3.hi, ac1[px]);
            }
        }
    }
#pragma unroll
    for (int px = 0; px < 2; px++) {
        float2 lo = __half22float2(ac0[px]);
        float2 hi = __half22float2(ac1[px]);
        float4 acc = make_float4(lo.x, lo.y, hi.x, hi.y);
        acc.x += __shfl_xor(acc.x, 32);
        acc.y += __shfl_xor(acc.y, 32);
        acc.z += __shfl_xor(acc.z, 32);
        acc.w += __shfl_xor(acc.w, 32);
        if (lane < 32) *(float4*)&outb[wv][px][c4] = acc;
    }
    __syncthreads();

    // final write: thread t: ch = t&127, qh = t>>7 -> float4 covering px qh*4..qh*4+3
    {
        int ch = tid & 127, qh = tid >> 7;
        float* op = out + ((size_t)b * NC + g * 128 + ch) * N1 + p0 + qh * 4;
        float4 v4 = make_float4(outb[qh * 2][0][ch], outb[qh * 2][1][ch],
                                outb[qh * 2 + 1][0][ch], outb[qh * 2 + 1][1][ch]);
        *(float4*)op = v4;
    }
}

extern "C" void kernel_launch(void* const* d_in, const int* in_sizes, int n_in,
                              void* d_out, int out_size, void* d_ws, size_t ws_size,
                              hipStream_t stream) {
    const float* x      = (const float*)d_in[0];
    const float* ln_g   = (const float*)d_in[1];
    const float* ln_b   = (const float*)d_in[2];
    const float* Wq     = (const float*)d_in[3];
    const float* Wk     = (const float*)d_in[4];
    const float* dw_w   = (const float*)d_in[5];
    const float* off_g  = (const float*)d_in[6];
    const float* off_bt = (const float*)d_in[7];
    const float* off_w  = (const float*)d_in[8];
    const float* off_b  = (const float*)d_in[9];
    const float* rpb    = (const float*)d_in[10];
    float* out = (float*)d_out;

    // Workspace layout. fp32 region then fp16 region. Total ≈ 8.87 MB. NO aliasing.
    float* ws = (float*)d_ws;
    float* WT4    = ws;                       // 32768   [64][128][4]
    float* q_pix  = WT4 + 32768;              // 294912  [2][2304][64]
    float* pred   = q_pix + 294912;           // 663552  [4][9216][18]
    float* dwT    = pred + 663552;            // 288     [9][32]
    float* wg2    = dwT + 288;                // 6912    [8][288][3]
    float* bsg2   = wg2 + 6912;               // 24      [8][3]
    __half* v_nhwc = (__half*)(bsg2 + 24);    // 1179648 h [4][2304][128]
    __half* k_nhwc = v_nhwc + 1179648;        // 294912 h  [4][2304][32]
    __half* tbuf_h = k_nhwc + 294912;         // 1179648 h [4][9216][32]

    kA_prep<<<1309, 256, 0, stream>>>(x, Wq, Wk, off_w, dw_w, off_b,
                                      v_nhwc, WT4, dwT, wg2, bsg2);
    k1_ln_qk<<<576, 512, 0, stream>>>(v_nhwc, ln_g, ln_b, WT4, q_pix, k_nhwc);
    k3_t<<<4608, 256, 0, stream>>>(q_pix, dwT, off_g, off_bt, tbuf_h);
    k4_pred<<<576, 512, 0, stream>>>(tbuf_h, wg2, bsg2, pred);
    k5_attn<<<4608, 256, 0, stream>>>(pred, q_pix, k_nhwc, v_nhwc, rpb, out);
}